// Round 1
// 146.679 us; speedup vs baseline: 1.0550x; 1.0550x over previous
//
#include <hip/hip_runtime.h>

// SparseLinearAttention: B=1, L=4096, H=16, D=64, BLKQ=BLKK=64, M=N=64, T=8.
// fp32 I/O. 4 dispatches: memset -> prep(K one-pass: kT,kfmT,kvsum,ksum,km
// [LDS-transpose km; balanced 4-row q-partials]; V->vT) -> post(topk + m2
// e-split over 64 blocks) -> fused attn (XCD-swizzled, 5 blk/CU, setprio).

#define NH   16
#define DH   64
#define NBLK 64
#define TSEL 8

typedef unsigned short u16;
typedef unsigned int   u32;
typedef __attribute__((ext_vector_type(8))) short short8;  // 8 bf16
typedef __attribute__((ext_vector_type(4))) float f4;

#define MFMA_BF16(a, b, c) __builtin_amdgcn_mfma_f32_16x16x32_bf16(a, b, c, 0, 0, 0)

__device__ __forceinline__ u16 f2bf_rne(float f) {
  u32 u = __float_as_uint(f);
  u += 0x7fffu + ((u >> 16) & 1u);
  return (u16)(u >> 16);
}
__device__ __forceinline__ u32 pk2(float a, float b) {
  return (u32)f2bf_rne(a) | ((u32)f2bf_rne(b) << 16);
}
__device__ __forceinline__ float bf2f(u16 u) { return __uint_as_float(((u32)u) << 16); }

// 8-bf16 fragment from a swizzled row-major bf16 tile (128B rows; logical
// 16B block j of row r stored at j^(r&7)).
__device__ __forceinline__ short8 frag_row(const u16* t, int row, int jblk) {
  return *(const short8*)((const char*)t + row * 128 + ((jblk ^ (row & 7)) * 16));
}

// ---------------- K_A: one-pass prep over K/V + kvsum + km + q-partials -----
// grid 1024 (XCD-swizzled: h = 2*(b&7) + (b>>9), n = (b>>3)&63), 256 thr.
// Thread = (row = tid&63, quarter = tid>>6): owns 16 contiguous cols of its
// row for both K and V. Same h<->XCD map as fused so kT/vT stay L2-local.
__global__ __launch_bounds__(256) void prep_kernel(const float* __restrict__ q,
                                                   const float* __restrict__ k,
                                                   const float* __restrict__ v,
                                                   u16* __restrict__ kT,
                                                   u16* __restrict__ vT,
                                                   float* __restrict__ kvsum,
                                                   float* __restrict__ ksum,
                                                   float* __restrict__ kmv,
                                                   float* __restrict__ qkp2) {
  __shared__ __align__(16) char vsl[8192];    // V^T bf16 swizzled
  __shared__ __align__(16) char kfm[8192];    // kfm^T bf16 swizzled
  __shared__ float kcol[64 * 65];             // raw K, column-major (km)
  __shared__ float redmx[256];
  __shared__ float redsm[256];
  __shared__ float kmred[256];
  __shared__ float ksred[256];
  int b = blockIdx.x;
  int n = (b >> 3) & 63;
  int h = 2 * (b & 7) + (b >> 9);
  int tid = threadIdx.x;
  int w = tid >> 6, lane = tid & 63;
  int row = lane, qd = w;
  int lq = lane & 15, quad = lane >> 4;

  // ---- K row segment (16 floats) ----
  float kv[16];
  {
    const float* kr = k + (size_t)(n * 64 + row) * 1024 + h * 64 + qd * 16;
#pragma unroll
    for (int c4 = 0; c4 < 4; c4++) {
      float4 a = *(const float4*)(kr + c4 * 4);
      kv[c4 * 4] = a.x; kv[c4 * 4 + 1] = a.y; kv[c4 * 4 + 2] = a.z; kv[c4 * 4 + 3] = a.w;
    }
  }
  // ---- kT global write (raw bf16, swizzled row layout) ----
  {
    char* ktb = (char*)(kT + ((size_t)(h * 64 + n)) * 4096);
    uint4 w0 = make_uint4(pk2(kv[0], kv[1]), pk2(kv[2], kv[3]),
                          pk2(kv[4], kv[5]), pk2(kv[6], kv[7]));
    uint4 w1 = make_uint4(pk2(kv[8], kv[9]), pk2(kv[10], kv[11]),
                          pk2(kv[12], kv[13]), pk2(kv[14], kv[15]));
    *(uint4*)(ktb + row * 128 + (((2 * qd) ^ (row & 7)) * 16)) = w0;
    *(uint4*)(ktb + row * 128 + (((2 * qd + 1) ^ (row & 7)) * 16)) = w1;
  }
  // ---- raw K into column-major LDS (for km) — both sides conflict-free ----
  {
#pragma unroll
    for (int j = 0; j < 16; j++) kcol[(qd * 16 + j) * 65 + row] = kv[j];
  }
  // ---- V^T into LDS (scalar transpose scatter, 2-way=free banks) ----
  {
    const float* vr = v + (size_t)(n * 64 + row) * 1024 + h * 64 + qd * 16;
    int kb = row >> 3, klo = row & 7;
#pragma unroll
    for (int c4 = 0; c4 < 4; c4++) {
      float4 a = *(const float4*)(vr + c4 * 4);
      float vv[4] = {a.x, a.y, a.z, a.w};
#pragma unroll
      for (int jj = 0; jj < 4; jj++) {
        int e = qd * 16 + c4 * 4 + jj;
        *(u16*)(vsl + e * 128 + ((kb ^ (e & 7)) * 16) + klo * 2) = f2bf_rne(vv[jj]);
      }
    }
  }
  // ---- row max partial ----
  {
    float mx = kv[0];
#pragma unroll
    for (int j = 1; j < 16; j++) mx = fmaxf(mx, kv[j]);
    redmx[qd * 64 + row] = mx;
  }
  __syncthreads();
  // ---- km partials: thread (c=tid&63, g=tid>>6) sums 16 rows of col c ----
  {
    int c = tid & 63, g = tid >> 6;
    float pk = 0.f;
#pragma unroll
    for (int i = 0; i < 16; i++) pk += kcol[c * 65 + g * 16 + i];
    kmred[g * 64 + c] = pk;
  }
  // ---- row softmax: max fold + exp + sum partial ----
  {
    float mx = fmaxf(fmaxf(redmx[row], redmx[64 + row]),
                     fmaxf(redmx[128 + row], redmx[192 + row]));
    float sm = 0.f;
#pragma unroll
    for (int j = 0; j < 16; j++) { kv[j] = __expf(kv[j] - mx); sm += kv[j]; }
    redsm[qd * 64 + row] = sm;
  }
  __syncthreads();
  if (tid < 64)
    kmv[h * 4096 + n * 64 + tid] =
        (kmred[tid] + kmred[64 + tid] + kmred[128 + tid] + kmred[192 + tid]) * (1.0f / 64.0f);
  {
    float sm = redsm[row] + redsm[64 + row] + redsm[128 + row] + redsm[192 + row];
    float inv = 1.0f / sm;
    int rb = row >> 3, rlo = row & 7;
#pragma unroll
    for (int j = 0; j < 16; j++) {
      int d = qd * 16 + j;
      *(u16*)(kfm + d * 128 + (((rb) ^ (d & 7)) * 16) + rlo * 2) = f2bf_rne(kv[j] * inv);
    }
  }
  __syncthreads();   // kfm + vsl complete

  // ---- vT global copy ----
  {
    uint4* vt_out = (uint4*)(vT + ((size_t)(h * 64 + n)) * 4096);
    vt_out[tid] = ((const uint4*)vsl)[tid];
    vt_out[256 + tid] = ((const uint4*)vsl)[256 + tid];
  }
  // ---- ksum partial: wave w sums key-blocks jb=2w,2w+1 over d=lane ----
  {
    float ks = 0.f;
    short8 x0 = frag_row((const u16*)kfm, lane, 2 * w);
    short8 x1 = frag_row((const u16*)kfm, lane, 2 * w + 1);
#pragma unroll
    for (int e = 0; e < 8; e++) ks += bf2f((u16)x0[e]) + bf2f((u16)x1[e]);
    ksred[tid] = ks;
  }
  // ---- kvsum MFMA: wave w owns d-tile dt=w ----
  {
    f4 acc[4];
    f4 zz = {0.f, 0.f, 0.f, 0.f};
#pragma unroll
    for (int et = 0; et < 4; et++) acc[et] = zz;
#pragma unroll
    for (int ks2 = 0; ks2 < 2; ks2++) {
      short8 a_ = frag_row((const u16*)kfm, w * 16 + lq, 4 * ks2 + quad);
#pragma unroll
      for (int et = 0; et < 4; et++)
        acc[et] = MFMA_BF16(a_, frag_row((const u16*)vsl, et * 16 + lq, 4 * ks2 + quad), acc[et]);
    }
#pragma unroll
    for (int et = 0; et < 4; et++)
#pragma unroll
      for (int r = 0; r < 4; r++)
        atomicAdd(&kvsum[h * 4096 + (w * 16 + quad * 4 + r) * 64 + et * 16 + lq],
                  acc[et][r]);
  }
  __syncthreads();
  if (tid < 64)
    atomicAdd(&ksum[h * 64 + tid], ksred[tid] + ksred[64 + tid] +
                                   ksred[128 + tid] + ksred[192 + tid]);

  // ---- balanced q partial: every block sums 4 rows (group index = h) ----
  {
    const float* base = q + ((size_t)(n * 64 + h * 4)) * 1024 + tid * 4;
    float4 acc = {0.f, 0.f, 0.f, 0.f};
#pragma unroll
    for (int i = 0; i < 4; i++) {
      float4 a = *(const float4*)(base + (size_t)i * 1024);
      acc.x += a.x; acc.y += a.y; acc.z += a.z; acc.w += a.w;
    }
    *(float4*)(qkp2 + ((size_t)(h * 64 + n)) * 1024 + tid * 4) = acc;
  }
}

// ---------------- K_B: post — topk (blocks 0..255) + m2 (blocks 256..319) --
// m2 split 4-way over e: block 256+4h+eq computes rows e in [eq*16, eq*16+16).
__global__ __launch_bounds__(256) void post_kernel(const float* __restrict__ qkp2,
                                                   const float* __restrict__ kmv,
                                                   const float* __restrict__ kvsum,
                                                   const float* __restrict__ wgt,
                                                   int* __restrict__ lut,
                                                   u16* __restrict__ m2t) {
  __shared__ float kv_s[64 * 65];
  __shared__ __align__(16) float wt[64 * 20];       // W^T slice: wt[j][e']
  __shared__ __align__(16) float qr_s[4][80];
  int bx = blockIdx.x, tid = threadIdx.x;
  if (bx < 256) {
    // ---- topk: h = bx>>4, wave w handles m = (bx&15)*4 + w ----
    int h = bx >> 4, w = tid >> 6, n = tid & 63;
    int m = (bx & 15) * 4 + w;
    float qsum = 0.f;
#pragma unroll
    for (int jg = 0; jg < 16; jg++)
      qsum += qkp2[((size_t)(jg * 64 + m)) * 1024 + h * 64 + n];
    qr_s[w][n] = qsum;
    __syncthreads();
    const float* kr = kmv + h * 4096 + n * 64;
    float s = 0.f;
#pragma unroll
    for (int d = 0; d < 64; d += 4) {
      float4 a = *(const float4*)(kr + d);
      float4 bb = *(const float4*)(&qr_s[w][d]);
      s += a.x * bb.x + a.y * bb.y + a.z * bb.z + a.w * bb.w;
    }
    float my = s;
    for (int t = 0; t < TSEL; t++) {
      float vv = my; int idx = n;
#pragma unroll
      for (int off = 1; off < 64; off <<= 1) {
        float ov = __shfl_xor(vv, off);
        int oi = __shfl_xor(idx, off);
        if (ov > vv || (ov == vv && oi < idx)) { vv = ov; idx = oi; }
      }
      if (n == 0) lut[(h * NBLK + m) * TSEL + t] = idx;
      if (n == idx) my = -INFINITY;
    }
  } else {
    // ---- m2 rows [eq*16, eq*16+16) for h ----
    int ib = bx - 256, h = ib >> 2, eq = ib & 3;
#pragma unroll
    for (int jj = 0; jj < 16; jj++) {
      int id2 = jj * 256 + tid;   // coalesced
      kv_s[(id2 >> 6) * 65 + (id2 & 63)] = kvsum[h * 4096 + id2];
    }
#pragma unroll
    for (int i = 0; i < 4; i++) {
      int f = i * 256 + tid;
      wt[(f & 63) * 20 + (f >> 6)] = wgt[(eq * 16 + (f >> 6)) * 64 + (f & 63)];
    }
    __syncthreads();
    int d = tid & 63, g = tid >> 6;   // g uniform per wave -> wt broadcast
    float4 acc = {0.f, 0.f, 0.f, 0.f};
    for (int jj = 0; jj < 64; jj++) {
      float kvj = kv_s[d * 65 + jj];
      float4 wv = *(const float4*)(&wt[jj * 20 + g * 4]);
      acc.x = fmaf(kvj, wv.x, acc.x);
      acc.y = fmaf(kvj, wv.y, acc.y);
      acc.z = fmaf(kvj, wv.z, acc.z);
      acc.w = fmaf(kvj, wv.w, acc.w);
    }
    char* base = (char*)m2t + (size_t)h * 8192;
    float av[4] = {acc.x, acc.y, acc.z, acc.w};
#pragma unroll
    for (int c = 0; c < 4; c++) {
      int ee = eq * 16 + g * 4 + c;
      *(u16*)(base + ee * 128 + (((d >> 3) ^ (ee & 7)) * 16) + (d & 7) * 2) = f2bf_rne(av[c]);
    }
  }
}

// ---------------- K_C: fused block-sparse + linear attention ----------------
// grid 1024 1D, XCD-swizzled: each XCD owns exactly 2 heads -> kT/vT working
// set 2MB per 4MB L2 (was 16MB thrash). 256 thr = 4 waves; wave w owns Q rows
// [w*16, w*16+16). Single K/V LDS buffer + register prefetch (2 barriers/it);
// m2 + ksum/bias staged into the buffer AFTER the K-loop -> 32 KB LDS exact
// -> 5 blocks/CU (20 waves).
__global__ __launch_bounds__(256, 5) void fused_attn_kernel(const float* __restrict__ q,
                                                            const u16* __restrict__ kT,
                                                            const u16* __restrict__ vT,
                                                            const int* __restrict__ lut,
                                                            const u16* __restrict__ m2t,
                                                            const float* __restrict__ ksum,
                                                            const float* __restrict__ bproj,
                                                            float* __restrict__ out) {
  __shared__ __align__(16) char smem[32768];
  // [0,8K) Q | [8K,24K) buf: K 8K + V^T 8K (m2 + ks/bias after loop) | [24K,32K) P
  int b = blockIdx.x;
  int m = (b >> 3) & 63;
  int h = 2 * (b & 7) + (b >> 9);
  int tid = threadIdx.x, w = tid >> 6, lane = tid & 63;
  int lq = lane & 15, quad = lane >> 4;
  u16* q_l = (u16*)smem;
  char* buf = smem + 8192;
  char* p_b = smem + 24576 + w * 2048;

  const int lb = (h * NBLK + m) * TSEL;
  int blks[8];
#pragma unroll
  for (int t = 0; t < 8; t++) blks[t] = lut[lb + t];

  { // stage Q (bf16 swizzled)
#pragma unroll
    for (int c = 0; c < 2; c++) {
      int lo = c * 4096 + tid * 16;
      int r = lo >> 7;
      int j = ((lo >> 4) & 7) ^ (r & 7);
      const float* gp = q + ((size_t)(m * 64 + r)) * 1024 + h * 64 + j * 8;
      float4 a = *(const float4*)gp;
      float4 bb = *(const float4*)(gp + 4);
      *(uint4*)(smem + lo) = make_uint4(pk2(a.x, a.y), pk2(a.z, a.w),
                                        pk2(bb.x, bb.y), pk2(bb.z, bb.w));
    }
  }
  { // stage K/V block 0
    const uint4* kt0 = (const uint4*)(kT + ((size_t)(h * 64 + blks[0])) * 4096);
    const uint4* vt0 = (const uint4*)(vT + ((size_t)(h * 64 + blks[0])) * 4096);
    ((uint4*)buf)[tid] = kt0[tid];
    ((uint4*)buf)[256 + tid] = kt0[256 + tid];
    ((uint4*)(buf + 8192))[tid] = vt0[tid];
    ((uint4*)(buf + 8192))[256 + tid] = vt0[256 + tid];
  }
  __syncthreads();

  const int qrow = w * 16 + lq;
  short8 qf[2];
#pragma unroll
  for (int ks = 0; ks < 2; ks++) qf[ks] = frag_row(q_l, qrow, 4 * ks + quad);

  float mrun = -INFINITY, lrun = 0.f;
  f4 o[4];
  f4 zz = {0.f, 0.f, 0.f, 0.f};
#pragma unroll
  for (int et = 0; et < 4; et++) o[et] = zz;

  const u16* kc = (const u16*)buf;
  const u16* vc = (const u16*)(buf + 8192);

  for (int t = 0; t < 8; t++) {
    // issue next-tile prefetch (16 transient VGPRs)
    uint4 pk0, pk1, pv0, pv1;
    if (t < 7) {
      const uint4* ktn = (const uint4*)(kT + ((size_t)(h * 64 + blks[t + 1])) * 4096);
      const uint4* vtn = (const uint4*)(vT + ((size_t)(h * 64 + blks[t + 1])) * 4096);
      pk0 = ktn[tid]; pk1 = ktn[256 + tid];
      pv0 = vtn[tid]; pv1 = vtn[256 + tid];
    }

    // S^T = K·Q^T
    f4 s[4];
#pragma unroll
    for (int kt = 0; kt < 4; kt++) s[kt] = zz;
    __builtin_amdgcn_s_setprio(1);
#pragma unroll
    for (int ks = 0; ks < 2; ks++)
#pragma unroll
      for (int kt = 0; kt < 4; kt++)
        s[kt] = MFMA_BF16(frag_row(kc, kt * 16 + lq, 4 * ks + quad), qf[ks], s[kt]);
    __builtin_amdgcn_s_setprio(0);

    // online softmax (16 scores/lane), P row lq -> wave-private slab
    float mp = -INFINITY;
#pragma unroll
    for (int kt = 0; kt < 4; kt++)
#pragma unroll
      for (int r = 0; r < 4; r++) mp = fmaxf(mp, s[kt][r]);
    mp = fmaxf(mp, __shfl_xor(mp, 16));
    mp = fmaxf(mp, __shfl_xor(mp, 32));
    mp *= 0.125f;
    // exact defer: lut is score-descending, so later tiles rarely raise the
    // max -> skip the rescale pass entirely when no lane's max grows.
    if (__any(mp > mrun)) {
      float mn = fmaxf(mrun, mp);
      float al = __expf(mrun - mn);
      mrun = mn;
      lrun *= al;
#pragma unroll
      for (int et = 0; et < 4; et++)
#pragma unroll
        for (int r = 0; r < 4; r++) o[et][r] *= al;
    }
    float rs_ = 0.f;
#pragma unroll
    for (int kt = 0; kt < 4; kt++) {
      float p0 = __expf(fmaf(s[kt][0], 0.125f, -mrun));
      float p1 = __expf(fmaf(s[kt][1], 0.125f, -mrun));
      float p2 = __expf(fmaf(s[kt][2], 0.125f, -mrun));
      float p3 = __expf(fmaf(s[kt][3], 0.125f, -mrun));
      rs_ += p0 + p1 + p2 + p3;
      u32 lo32 = (__float_as_uint(p0) >> 16) | (__float_as_uint(p1) & 0xffff0000u);
      u32 hi32 = (__float_as_uint(p2) >> 16) | (__float_as_uint(p3) & 0xffff0000u);
      int addr = lq * 128 + (((kt * 2 + (quad >> 1)) ^ (lq & 7)) * 16) + (quad & 1) * 8;
      *(uint2*)(p_b + addr) = make_uint2(lo32, hi32);
    }
    rs_ += __shfl_xor(rs_, 16);
    rs_ += __shfl_xor(rs_, 32);
    lrun += rs_;

    // O^T += V^T · P^T
    __builtin_amdgcn_s_setprio(1);
#pragma unroll
    for (int ks = 0; ks < 2; ks++) {
      short8 pf = frag_row((const u16*)p_b, lq, 4 * ks + quad);
#pragma unroll
      for (int et = 0; et < 4; et++)
        o[et] = MFMA_BF16(frag_row(vc, et * 16 + lq, 4 * ks + quad), pf, o[et]);
    }
    __builtin_amdgcn_s_setprio(0);

    // rotate buffer: wait for all readers, drain prefetch, publish
    if (t < 7) {
      __syncthreads();
      ((uint4*)buf)[tid] = pk0;
      ((uint4*)buf)[256 + tid] = pk1;
      ((uint4*)(buf + 8192))[tid] = pv0;
      ((uint4*)(buf + 8192))[256 + tid] = pv1;
      __syncthreads();
    }
  }

  // ---- stage m2 + ksum + bias into buf (reuse), then fused linear attn ----
  __syncthreads();
  {
    const uint4* src = (const uint4*)((const char*)m2t + (size_t)h * 8192);
    ((uint4*)buf)[tid] = src[tid];
    ((uint4*)buf)[256 + tid] = src[256 + tid];
    if (tid < 64) {
      ((float*)(buf + 8192))[tid] = ksum[h * 64 + tid];
      ((float*)(buf + 8448))[tid] = bproj[tid];
    }
  }
  __syncthreads();
  u16* m2_l = (u16*)buf;
  float* ks_s = (float*)(buf + 8192);
  float* b_s = (float*)(buf + 8448);

  short8 qa = frag_row(q_l, qrow, 2 * quad);
  short8 qb = frag_row(q_l, qrow, 2 * quad + 1);
  float ev[16];
  float mx = -INFINITY;
#pragma unroll
  for (int j = 0; j < 8; j++) { float x = bf2f((u16)qa[j]); ev[j] = x; mx = fmaxf(mx, x); }
#pragma unroll
  for (int j = 0; j < 8; j++) { float x = bf2f((u16)qb[j]); ev[8 + j] = x; mx = fmaxf(mx, x); }
  mx = fmaxf(mx, __shfl_xor(mx, 16));
  mx = fmaxf(mx, __shfl_xor(mx, 32));
  float sum = 0.f, eks = 0.f;
#pragma unroll
  for (int j = 0; j < 16; j++) {
    float e = __expf(ev[j] - mx);
    ev[j] = e;
    sum += e;
    eks += e * ks_s[quad * 16 + j];
  }
  sum += __shfl_xor(sum, 16); sum += __shfl_xor(sum, 32);
  eks += __shfl_xor(eks, 16); eks += __shfl_xor(eks, 32);
  float invs = 1.0f / sum;
  float den = fmaf(eks, invs, 1e-6f);
  float scale = invs / den;
  // E row lq -> wave slab (blocks 2*quad, 2*quad+1)
  uint4 e0v = make_uint4(pk2(ev[0], ev[1]), pk2(ev[2], ev[3]),
                         pk2(ev[4], ev[5]), pk2(ev[6], ev[7]));
  uint4 e1v = make_uint4(pk2(ev[8], ev[9]), pk2(ev[10], ev[11]),
                         pk2(ev[12], ev[13]), pk2(ev[14], ev[15]));
  *(uint4*)(p_b + lq * 128 + (((2 * quad) ^ (lq & 7)) * 16)) = e0v;
  *(uint4*)(p_b + lq * 128 + (((2 * quad + 1) ^ (lq & 7)) * 16)) = e1v;

  f4 oc[4];
  f4 zz2 = {0.f, 0.f, 0.f, 0.f};
#pragma unroll
  for (int et = 0; et < 4; et++) oc[et] = zz2;
  __builtin_amdgcn_s_setprio(1);
#pragma unroll
  for (int ks2 = 0; ks2 < 2; ks2++) {
    short8 ef = frag_row((const u16*)p_b, lq, 4 * ks2 + quad);
#pragma unroll
    for (int et = 0; et < 4; et++)
      oc[et] = MFMA_BF16(frag_row(m2_l, et * 16 + lq, 4 * ks2 + quad), ef, oc[et]);
  }
  __builtin_amdgcn_s_setprio(0);

  // ---- single write: out = o_s/l + o_l*scale + bias ----
  float invl = 1.0f / lrun;
  float* gp = out + ((size_t)(m * 64 + qrow)) * 1024 + h * 64 + quad * 4;
#pragma unroll
  for (int et = 0; et < 4; et++) {
    int e0 = et * 16 + quad * 4;
    float4 ov;
    ov.x = o[et][0] * invl + oc[et][0] * scale + b_s[e0 + 0];
    ov.y = o[et][1] * invl + oc[et][1] * scale + b_s[e0 + 1];
    ov.z = o[et][2] * invl + oc[et][2] * scale + b_s[e0 + 2];
    ov.w = o[et][3] * invl + oc[et][3] * scale + b_s[e0 + 3];
    *(float4*)(gp + et * 16) = ov;
  }
}

extern "C" void kernel_launch(void* const* d_in, const int* in_sizes, int n_in,
                              void* d_out, int out_size, void* d_ws, size_t ws_size,
                              hipStream_t stream) {
  const float* q = (const float*)d_in[0];
  const float* k = (const float*)d_in[1];
  const float* v = (const float*)d_in[2];
  const float* w = (const float*)d_in[3];
  const float* b = (const float*)d_in[4];
  float* out = (float*)d_out;

  // ws: kT 8MB u16 | vT 8MB u16 | qkp2 4MB f32 | kmv 256KB f32 | lut 32KB |
  //     kvsum 256KB f32 | ksum 4KB f32 | m2t 128KB u16
  u16* kT = (u16*)d_ws;
  u16* vT = kT + 4194304;
  float* qkp2 = (float*)(vT + 4194304);
  float* kmv = qkp2 + 1048576;
  int* lut = (int*)(kmv + 65536);
  float* kvsum = (float*)(lut + 8192);
  float* ksum = kvsum + 65536;
  u16* m2t = (u16*)(ksum + 1024);

  hipMemsetAsync(kvsum, 0, (65536 + 1024) * sizeof(float), stream);
  prep_kernel<<<1024, 256, 0, stream>>>(q, k, v, kT, vT, kvsum, ksum, kmv, qkp2);
  post_kernel<<<320, 256, 0, stream>>>(qkp2, kmv, kvsum, w, lut, m2t);
  fused_attn_kernel<<<1024, 256, 0, stream>>>(q, kT, vT, lut, m2t, ksum, b, out);
}

// Round 2
// 136.980 us; speedup vs baseline: 1.1297x; 1.0708x over previous
//
#include <hip/hip_runtime.h>

// SparseLinearAttention: B=1, L=4096, H=16, D=64, BLKQ=BLKK=64, M=N=64, T=8.
// fp32 I/O. 3 dispatches (no memset, no atomics):
//   prep(K one-pass: kT,kfmT,kvsum-partials,ksum-partials,km; V->vT)
// -> post(reduce kvsum partials + apply W -> m2; ksum)  [256 blocks]
// -> fused attn (topk in-block, XCD-swizzled, 24KB LDS -> 6 blk/CU).

#define NH   16
#define DH   64
#define NBLK 64
#define TSEL 8

typedef unsigned short u16;
typedef unsigned int   u32;
typedef __attribute__((ext_vector_type(8))) short short8;  // 8 bf16
typedef __attribute__((ext_vector_type(4))) float f4;
typedef __attribute__((ext_vector_type(4))) u32 u32x4;

#define MFMA_BF16(a, b, c) __builtin_amdgcn_mfma_f32_16x16x32_bf16(a, b, c, 0, 0, 0)

__device__ __forceinline__ u16 f2bf_rne(float f) {
  u32 u = __float_as_uint(f);
  u += 0x7fffu + ((u >> 16) & 1u);
  return (u16)(u >> 16);
}
__device__ __forceinline__ u32 pk2(float a, float b) {
  return (u32)f2bf_rne(a) | ((u32)f2bf_rne(b) << 16);
}
__device__ __forceinline__ float bf2f(u16 u) { return __uint_as_float(((u32)u) << 16); }

// 8-bf16 fragment from a swizzled row-major bf16 tile (128B rows; logical
// 16B block j of row r stored at j^(r&7)).
__device__ __forceinline__ short8 frag_row(const u16* t, int row, int jblk) {
  return *(const short8*)((const char*)t + row * 128 + ((jblk ^ (row & 7)) * 16));
}

// ---------------- K_A: one-pass prep over K/V ------------------------------
// grid 1024 (XCD-swizzled: h = 2*(b&7) + (b>>9), n = (b>>3)&63), 256 thr.
// Thread = (row = tid&63, quarter = tid>>6): owns 16 contiguous cols of its
// row for both K and V. Writes kT/vT (bf16 swizzled), kmv, and per-(h,n)
// fp32 partials for kvsum (kvp) and ksum (ksp) — no atomics anywhere.
__global__ __launch_bounds__(256) void prep_kernel(const float* __restrict__ k,
                                                   const float* __restrict__ v,
                                                   u16* __restrict__ kT,
                                                   u16* __restrict__ vT,
                                                   float* __restrict__ kvp,
                                                   float* __restrict__ ksp,
                                                   float* __restrict__ kmv) {
  __shared__ __align__(16) char vsl[8192];    // V^T bf16 swizzled
  __shared__ __align__(16) char kfm[8192];    // kfm^T bf16 swizzled
  __shared__ float kcol[64 * 65];             // raw K, column-major (km)
  __shared__ float redmx[256];
  __shared__ float redsm[256];
  __shared__ float kmred[256];
  __shared__ float ksred[256];
  int b = blockIdx.x;
  int n = (b >> 3) & 63;
  int h = 2 * (b & 7) + (b >> 9);
  int tid = threadIdx.x;
  int w = tid >> 6, lane = tid & 63;
  int row = lane, qd = w;
  int lq = lane & 15, quad = lane >> 4;

  // ---- K row segment (16 floats) ----
  float kv[16];
  {
    const float* kr = k + (size_t)(n * 64 + row) * 1024 + h * 64 + qd * 16;
#pragma unroll
    for (int c4 = 0; c4 < 4; c4++) {
      float4 a = *(const float4*)(kr + c4 * 4);
      kv[c4 * 4] = a.x; kv[c4 * 4 + 1] = a.y; kv[c4 * 4 + 2] = a.z; kv[c4 * 4 + 3] = a.w;
    }
  }
  // ---- kT global write (raw bf16, swizzled row layout) ----
  {
    char* ktb = (char*)(kT + ((size_t)(h * 64 + n)) * 4096);
    uint4 w0 = make_uint4(pk2(kv[0], kv[1]), pk2(kv[2], kv[3]),
                          pk2(kv[4], kv[5]), pk2(kv[6], kv[7]));
    uint4 w1 = make_uint4(pk2(kv[8], kv[9]), pk2(kv[10], kv[11]),
                          pk2(kv[12], kv[13]), pk2(kv[14], kv[15]));
    *(uint4*)(ktb + row * 128 + (((2 * qd) ^ (row & 7)) * 16)) = w0;
    *(uint4*)(ktb + row * 128 + (((2 * qd + 1) ^ (row & 7)) * 16)) = w1;
  }
  // ---- raw K into column-major LDS (for km) ----
  {
#pragma unroll
    for (int j = 0; j < 16; j++) kcol[(qd * 16 + j) * 65 + row] = kv[j];
  }
  // ---- V^T into LDS (scalar transpose scatter, 2-way=free banks) ----
  {
    const float* vr = v + (size_t)(n * 64 + row) * 1024 + h * 64 + qd * 16;
    int kb = row >> 3, klo = row & 7;
#pragma unroll
    for (int c4 = 0; c4 < 4; c4++) {
      float4 a = *(const float4*)(vr + c4 * 4);
      float vv[4] = {a.x, a.y, a.z, a.w};
#pragma unroll
      for (int jj = 0; jj < 4; jj++) {
        int e = qd * 16 + c4 * 4 + jj;
        *(u16*)(vsl + e * 128 + ((kb ^ (e & 7)) * 16) + klo * 2) = f2bf_rne(vv[jj]);
      }
    }
  }
  // ---- row max partial ----
  {
    float mx = kv[0];
#pragma unroll
    for (int j = 1; j < 16; j++) mx = fmaxf(mx, kv[j]);
    redmx[qd * 64 + row] = mx;
  }
  __syncthreads();
  // ---- km partials: thread (c=tid&63, g=tid>>6) sums 16 rows of col c ----
  {
    int c = tid & 63, g = tid >> 6;
    float pk = 0.f;
#pragma unroll
    for (int i = 0; i < 16; i++) pk += kcol[c * 65 + g * 16 + i];
    kmred[g * 64 + c] = pk;
  }
  // ---- row softmax: max fold + exp + sum partial ----
  {
    float mx = fmaxf(fmaxf(redmx[row], redmx[64 + row]),
                     fmaxf(redmx[128 + row], redmx[192 + row]));
    float sm = 0.f;
#pragma unroll
    for (int j = 0; j < 16; j++) { kv[j] = __expf(kv[j] - mx); sm += kv[j]; }
    redsm[qd * 64 + row] = sm;
  }
  __syncthreads();
  if (tid < 64)
    kmv[h * 4096 + n * 64 + tid] =
        (kmred[tid] + kmred[64 + tid] + kmred[128 + tid] + kmred[192 + tid]) * (1.0f / 64.0f);
  {
    float sm = redsm[row] + redsm[64 + row] + redsm[128 + row] + redsm[192 + row];
    float inv = 1.0f / sm;
    int rb = row >> 3, rlo = row & 7;
#pragma unroll
    for (int j = 0; j < 16; j++) {
      int d = qd * 16 + j;
      *(u16*)(kfm + d * 128 + (((rb) ^ (d & 7)) * 16) + rlo * 2) = f2bf_rne(kv[j] * inv);
    }
  }
  __syncthreads();   // kfm + vsl complete

  // ---- vT global copy ----
  {
    uint4* vt_out = (uint4*)(vT + ((size_t)(h * 64 + n)) * 4096);
    vt_out[tid] = ((const uint4*)vsl)[tid];
    vt_out[256 + tid] = ((const uint4*)vsl)[256 + tid];
  }
  // ---- ksum partial: wave w sums key-blocks jb=2w,2w+1 over d=lane ----
  {
    float ks = 0.f;
    short8 x0 = frag_row((const u16*)kfm, lane, 2 * w);
    short8 x1 = frag_row((const u16*)kfm, lane, 2 * w + 1);
#pragma unroll
    for (int e = 0; e < 8; e++) ks += bf2f((u16)x0[e]) + bf2f((u16)x1[e]);
    ksred[tid] = ks;
  }
  // ---- kvsum MFMA partial -> plain global store (no atomics) ----
  {
    f4 acc[4];
    f4 zz = {0.f, 0.f, 0.f, 0.f};
#pragma unroll
    for (int et = 0; et < 4; et++) acc[et] = zz;
#pragma unroll
    for (int ks2 = 0; ks2 < 2; ks2++) {
      short8 a_ = frag_row((const u16*)kfm, w * 16 + lq, 4 * ks2 + quad);
#pragma unroll
      for (int et = 0; et < 4; et++)
        acc[et] = MFMA_BF16(a_, frag_row((const u16*)vsl, et * 16 + lq, 4 * ks2 + quad), acc[et]);
    }
    float* kvb = kvp + ((size_t)(h * 64 + n)) * 4096;
#pragma unroll
    for (int r = 0; r < 4; r++)
#pragma unroll
      for (int et = 0; et < 4; et++)
        kvb[(w * 16 + quad * 4 + r) * 64 + et * 16 + lq] = acc[et][r];
  }
  __syncthreads();
  if (tid < 64)
    ksp[((size_t)(h * 64 + n)) * 64 + tid] = ksred[tid] + ksred[64 + tid] +
                                             ksred[128 + tid] + ksred[192 + tid];
}

// ---------------- K_B: post — reduce kvsum partials + apply W -> m2 --------
// grid 256: block (h = bx>>4, dq = bx&15) owns d-rows [dq*4, dq*4+4).
// Reduces 64 fp32 partial tiles (coalesced), multiplies by W^T, writes the
// bf16-swizzled m2 slice. dq==0 blocks also reduce ksum partials.
__global__ __launch_bounds__(256) void post_kernel(const float* __restrict__ kvp,
                                                   const float* __restrict__ ksp,
                                                   const float* __restrict__ wgt,
                                                   u16* __restrict__ m2t,
                                                   float* __restrict__ ksum) {
  __shared__ float kr[4][64];
  __shared__ float wl[64 * 65];   // wl[e*65 + j] = W[e][j]
  int bx = blockIdx.x, tid = threadIdx.x;
  int h = bx >> 4, dq = bx & 15;
  int j = tid & 63, rr = tid >> 6;

  // reduce kvsum row (dq*4+rr), col j over 64 n-partials
  {
    size_t off = (size_t)(dq * 4 + rr) * 64 + j;
    const float* base = kvp + (size_t)h * 64 * 4096 + off;
    float s0 = 0.f, s1 = 0.f, s2 = 0.f, s3 = 0.f;
#pragma unroll
    for (int n4 = 0; n4 < 16; n4++) {
      s0 += base[(size_t)(n4 * 4 + 0) * 4096];
      s1 += base[(size_t)(n4 * 4 + 1) * 4096];
      s2 += base[(size_t)(n4 * 4 + 2) * 4096];
      s3 += base[(size_t)(n4 * 4 + 3) * 4096];
    }
    kr[rr][j] = (s0 + s1) + (s2 + s3);
  }
  // stage W (coalesced read, conflict-free LDS)
#pragma unroll
  for (int i = 0; i < 16; i++) {
    int f = i * 256 + tid;
    wl[(f >> 6) * 65 + (f & 63)] = wgt[f];
  }
  __syncthreads();

  // m2[e][d] slice: thread (rr2 = tid>>6, e = tid&63), d = dq*4+rr2
  {
    int e = tid & 63, rr2 = tid >> 6;
    float acc = 0.f;
#pragma unroll
    for (int jj = 0; jj < 64; jj++) acc = fmaf(kr[rr2][jj], wl[e * 65 + jj], acc);
    int d = dq * 4 + rr2;
    *(u16*)((char*)m2t + (size_t)h * 8192 + e * 128 +
            (((d >> 3) ^ (e & 7)) * 16) + (d & 7) * 2) = f2bf_rne(acc);
  }
  // ksum reduction (once per h)
  if (dq == 0 && tid < 64) {
    const float* base = ksp + (size_t)h * 64 * 64 + tid;
    float s = 0.f;
#pragma unroll
    for (int n = 0; n < 64; n++) s += base[(size_t)n * 64];
    ksum[h * 64 + tid] = s;
  }
}

// ---------------- K_C: fused topk + block-sparse + linear attention --------
// grid 1024 1D, XCD-swizzled (each XCD owns 2 heads -> kT/vT/km L2-local).
// 256 thr = 4 waves; wave w owns Q rows [w*16, w*16+16). Per-block topk
// (q-block mean vs km, butterfly argmax, tie->lower idx). Q fragments load
// straight from global (no Q LDS) -> 24 KB LDS -> 6 blocks/CU.
__global__ __launch_bounds__(256, 6) void fused_attn_kernel(const float* __restrict__ q,
                                                            const u16* __restrict__ kT,
                                                            const u16* __restrict__ vT,
                                                            const float* __restrict__ kmv,
                                                            const u16* __restrict__ m2t,
                                                            const float* __restrict__ ksum,
                                                            const float* __restrict__ bproj,
                                                            float* __restrict__ out) {
  __shared__ __align__(16) char smem[24576];
  // K-loop era: [0,8K) K | [8K,16K) V^T | [16K,24K) P (2K/wave)
  // topk era:   [0,16.6K) km padded | [20K..] qm scratch
  // post-loop:  [0,8K) m2 | [8K..) ksum/bias
  int b = blockIdx.x;
  int m = (b >> 3) & 63;
  int h = 2 * (b & 7) + (b >> 9);
  int tid = threadIdx.x, w = tid >> 6, lane = tid & 63;
  int lq = lane & 15, quad = lane >> 4;
  char* buf = smem;
  char* p_b = smem + 16384 + w * 2048;
  float* km_s = (float*)smem;             // stride 65
  float* qmp = (float*)(smem + 20480);    // 256 floats
  float* qmf = (float*)(smem + 21504);    // 64 floats

  // ---- topk phase: q-block mean + scores vs km + butterfly top-8 ----
  {
    int c = tid & 63, g = tid >> 6;
    const float* qcol = q + ((size_t)(m * 64 + g * 16)) * 1024 + h * 64 + c;
    float qp = 0.f;
#pragma unroll
    for (int i = 0; i < 16; i++) qp += qcol[(size_t)i * 1024];
    qmp[g * 64 + c] = qp;
#pragma unroll
    for (int i = 0; i < 16; i++) {
      int idx = i * 256 + tid;
      km_s[(idx >> 6) * 65 + (idx & 63)] = kmv[h * 4096 + idx];
    }
  }
  __syncthreads();
  if (tid < 64) qmf[tid] = qmp[tid] + qmp[64 + tid] + qmp[128 + tid] + qmp[192 + tid];
  __syncthreads();
  int blks[8];
  {
    int n = lane;
    float s = 0.f;
#pragma unroll
    for (int d = 0; d < 64; d++) s += qmf[d] * km_s[n * 65 + d];
    float my = s;
#pragma unroll
    for (int t = 0; t < TSEL; t++) {
      float vv = my; int idx = n;
#pragma unroll
      for (int off = 1; off < 64; off <<= 1) {
        float ov = __shfl_xor(vv, off);
        int oi = __shfl_xor(idx, off);
        if (ov > vv || (ov == vv && oi < idx)) { vv = ov; idx = oi; }
      }
      int sel = __builtin_amdgcn_readfirstlane(idx);
      blks[t] = sel;
      if (n == sel) my = -INFINITY;
    }
  }
  __syncthreads();   // km_s dead; buf reusable

  // ---- Q fragments straight from global (bf16 pack in-reg) ----
  const int qrow = w * 16 + lq;
  const float* qr_g = q + ((size_t)(m * 64 + qrow)) * 1024 + h * 64;
  short8 qf[2];
#pragma unroll
  for (int ks = 0; ks < 2; ks++) {
    const float* gp = qr_g + (4 * ks + quad) * 8;
    float4 a = *(const float4*)gp;
    float4 bb = *(const float4*)(gp + 4);
    u32x4 tt = {pk2(a.x, a.y), pk2(a.z, a.w), pk2(bb.x, bb.y), pk2(bb.z, bb.w)};
    qf[ks] = __builtin_bit_cast(short8, tt);
  }

  { // stage K/V block 0
    const uint4* kt0 = (const uint4*)(kT + ((size_t)(h * 64 + blks[0])) * 4096);
    const uint4* vt0 = (const uint4*)(vT + ((size_t)(h * 64 + blks[0])) * 4096);
    ((uint4*)buf)[tid] = kt0[tid];
    ((uint4*)buf)[256 + tid] = kt0[256 + tid];
    ((uint4*)(buf + 8192))[tid] = vt0[tid];
    ((uint4*)(buf + 8192))[256 + tid] = vt0[256 + tid];
  }
  __syncthreads();

  float mrun = -INFINITY, lrun = 0.f;
  f4 o[4];
  f4 zz = {0.f, 0.f, 0.f, 0.f};
#pragma unroll
  for (int et = 0; et < 4; et++) o[et] = zz;

  const u16* kc = (const u16*)buf;
  const u16* vc = (const u16*)(buf + 8192);

  for (int t = 0; t < 8; t++) {
    // issue next-tile prefetch (16 transient VGPRs)
    uint4 pk0, pk1, pv0, pv1;
    if (t < 7) {
      const uint4* ktn = (const uint4*)(kT + ((size_t)(h * 64 + blks[t + 1])) * 4096);
      const uint4* vtn = (const uint4*)(vT + ((size_t)(h * 64 + blks[t + 1])) * 4096);
      pk0 = ktn[tid]; pk1 = ktn[256 + tid];
      pv0 = vtn[tid]; pv1 = vtn[256 + tid];
    }

    // S^T = K·Q^T
    f4 s[4];
#pragma unroll
    for (int kt = 0; kt < 4; kt++) s[kt] = zz;
    __builtin_amdgcn_s_setprio(1);
#pragma unroll
    for (int ks = 0; ks < 2; ks++)
#pragma unroll
      for (int kt = 0; kt < 4; kt++)
        s[kt] = MFMA_BF16(frag_row(kc, kt * 16 + lq, 4 * ks + quad), qf[ks], s[kt]);
    __builtin_amdgcn_s_setprio(0);

    // online softmax (16 scores/lane), P row lq -> wave-private slab
    float mp = -INFINITY;
#pragma unroll
    for (int kt = 0; kt < 4; kt++)
#pragma unroll
      for (int r = 0; r < 4; r++) mp = fmaxf(mp, s[kt][r]);
    mp = fmaxf(mp, __shfl_xor(mp, 16));
    mp = fmaxf(mp, __shfl_xor(mp, 32));
    mp *= 0.125f;
    // exact defer: lut is score-descending, so later tiles rarely raise the
    // max -> skip the rescale pass entirely when no lane's max grows.
    if (__any(mp > mrun)) {
      float mn = fmaxf(mrun, mp);
      float al = __expf(mrun - mn);
      mrun = mn;
      lrun *= al;
#pragma unroll
      for (int et = 0; et < 4; et++)
#pragma unroll
        for (int r = 0; r < 4; r++) o[et][r] *= al;
    }
    float rs_ = 0.f;
#pragma unroll
    for (int kt = 0; kt < 4; kt++) {
      float p0 = __expf(fmaf(s[kt][0], 0.125f, -mrun));
      float p1 = __expf(fmaf(s[kt][1], 0.125f, -mrun));
      float p2 = __expf(fmaf(s[kt][2], 0.125f, -mrun));
      float p3 = __expf(fmaf(s[kt][3], 0.125f, -mrun));
      rs_ += p0 + p1 + p2 + p3;
      u32 lo32 = (__float_as_uint(p0) >> 16) | (__float_as_uint(p1) & 0xffff0000u);
      u32 hi32 = (__float_as_uint(p2) >> 16) | (__float_as_uint(p3) & 0xffff0000u);
      int addr = lq * 128 + (((kt * 2 + (quad >> 1)) ^ (lq & 7)) * 16) + (quad & 1) * 8;
      *(uint2*)(p_b + addr) = make_uint2(lo32, hi32);
    }
    rs_ += __shfl_xor(rs_, 16);
    rs_ += __shfl_xor(rs_, 32);
    lrun += rs_;

    // O^T += V^T · P^T
    __builtin_amdgcn_s_setprio(1);
#pragma unroll
    for (int ks = 0; ks < 2; ks++) {
      short8 pf = frag_row((const u16*)p_b, lq, 4 * ks + quad);
#pragma unroll
      for (int et = 0; et < 4; et++)
        o[et] = MFMA_BF16(frag_row(vc, et * 16 + lq, 4 * ks + quad), pf, o[et]);
    }
    __builtin_amdgcn_s_setprio(0);

    // rotate buffer: wait for all readers, drain prefetch, publish
    if (t < 7) {
      __syncthreads();
      ((uint4*)buf)[tid] = pk0;
      ((uint4*)buf)[256 + tid] = pk1;
      ((uint4*)(buf + 8192))[tid] = pv0;
      ((uint4*)(buf + 8192))[256 + tid] = pv1;
      __syncthreads();
    }
  }

  // ---- stage m2 + ksum + bias into buf (reuse), then fused linear attn ----
  __syncthreads();
  {
    const uint4* src = (const uint4*)((const char*)m2t + (size_t)h * 8192);
    ((uint4*)buf)[tid] = src[tid];
    ((uint4*)buf)[256 + tid] = src[256 + tid];
    if (tid < 64) {
      ((float*)(buf + 8192))[tid] = ksum[h * 64 + tid];
      ((float*)(buf + 8448))[tid] = bproj[tid];
    }
  }
  __syncthreads();
  u16* m2_l = (u16*)buf;
  float* ks_s = (float*)(buf + 8192);
  float* b_s = (float*)(buf + 8448);

  // linear-attn feature map from fp32 q row (cols quad*16..+16)
  float ev[16];
  float mx = -INFINITY;
#pragma unroll
  for (int c4 = 0; c4 < 4; c4++) {
    float4 a = *(const float4*)(qr_g + quad * 16 + c4 * 4);
    ev[c4 * 4] = a.x; ev[c4 * 4 + 1] = a.y; ev[c4 * 4 + 2] = a.z; ev[c4 * 4 + 3] = a.w;
    mx = fmaxf(mx, fmaxf(fmaxf(a.x, a.y), fmaxf(a.z, a.w)));
  }
  mx = fmaxf(mx, __shfl_xor(mx, 16));
  mx = fmaxf(mx, __shfl_xor(mx, 32));
  float sum = 0.f, eks = 0.f;
#pragma unroll
  for (int j = 0; j < 16; j++) {
    float e = __expf(ev[j] - mx);
    ev[j] = e;
    sum += e;
    eks += e * ks_s[quad * 16 + j];
  }
  sum += __shfl_xor(sum, 16); sum += __shfl_xor(sum, 32);
  eks += __shfl_xor(eks, 16); eks += __shfl_xor(eks, 32);
  float invs = 1.0f / sum;
  float den = fmaf(eks, invs, 1e-6f);
  float scale = invs / den;
  // E row lq -> wave slab (blocks 2*quad, 2*quad+1)
  uint4 e0v = make_uint4(pk2(ev[0], ev[1]), pk2(ev[2], ev[3]),
                         pk2(ev[4], ev[5]), pk2(ev[6], ev[7]));
  uint4 e1v = make_uint4(pk2(ev[8], ev[9]), pk2(ev[10], ev[11]),
                         pk2(ev[12], ev[13]), pk2(ev[14], ev[15]));
  *(uint4*)(p_b + lq * 128 + (((2 * quad) ^ (lq & 7)) * 16)) = e0v;
  *(uint4*)(p_b + lq * 128 + (((2 * quad + 1) ^ (lq & 7)) * 16)) = e1v;

  f4 oc[4];
  f4 zz2 = {0.f, 0.f, 0.f, 0.f};
#pragma unroll
  for (int et = 0; et < 4; et++) oc[et] = zz2;
  __builtin_amdgcn_s_setprio(1);
#pragma unroll
  for (int ks2 = 0; ks2 < 2; ks2++) {
    short8 ef = frag_row((const u16*)p_b, lq, 4 * ks2 + quad);
#pragma unroll
    for (int et = 0; et < 4; et++)
      oc[et] = MFMA_BF16(frag_row(m2_l, et * 16 + lq, 4 * ks2 + quad), ef, oc[et]);
  }
  __builtin_amdgcn_s_setprio(0);

  // ---- single write: out = o_s/l + o_l*scale + bias ----
  float invl = 1.0f / lrun;
  float* gp = out + ((size_t)(m * 64 + qrow)) * 1024 + h * 64 + quad * 4;
#pragma unroll
  for (int et = 0; et < 4; et++) {
    int e0 = et * 16 + quad * 4;
    float4 ov;
    ov.x = o[et][0] * invl + oc[et][0] * scale + b_s[e0 + 0];
    ov.y = o[et][1] * invl + oc[et][1] * scale + b_s[e0 + 1];
    ov.z = o[et][2] * invl + oc[et][2] * scale + b_s[e0 + 2];
    ov.w = o[et][3] * invl + oc[et][3] * scale + b_s[e0 + 3];
    *(float4*)(gp + et * 16) = ov;
  }
}

extern "C" void kernel_launch(void* const* d_in, const int* in_sizes, int n_in,
                              void* d_out, int out_size, void* d_ws, size_t ws_size,
                              hipStream_t stream) {
  const float* q = (const float*)d_in[0];
  const float* k = (const float*)d_in[1];
  const float* v = (const float*)d_in[2];
  const float* w = (const float*)d_in[3];
  const float* b = (const float*)d_in[4];
  float* out = (float*)d_out;

  // ws: kT 8MB u16 | vT 8MB u16 | kvp 16MB f32 | ksp 256KB f32 |
  //     kmv 256KB f32 | ksum 4KB f32 | m2t 128KB u16   (~32.6MB of 256MB)
  u16* kT = (u16*)d_ws;
  u16* vT = kT + 4194304;
  float* kvp = (float*)(vT + 4194304);
  float* ksp = kvp + 4194304;
  float* kmv = ksp + 65536;
  float* ksum = kmv + 65536;
  u16* m2t = (u16*)(ksum + 1024);

  prep_kernel<<<1024, 256, 0, stream>>>(k, v, kT, vT, kvp, ksp, kmv);
  post_kernel<<<256, 256, 0, stream>>>(kvp, ksp, w, m2t, ksum);
  fused_attn_kernel<<<1024, 256, 0, stream>>>(q, kT, vT, kmv, m2t, ksum, b, out);
}